// Round 13
// baseline (77.023 us; speedup 1.0000x reference)
//
#include <hip/hip_runtime.h>
#include <hip/hip_bf16.h>

#define NPTS   300
#define HW_SZ  1920
#define TOTAL  (NPTS * HW_SZ)    // 576000
#define K      256               // 128 cos/P || 128 sin/Q
#define NCOL   2400              // columns c = n*8 + h
#define NPAD   2432              // 38 * 64
#define L2T128 0.10381025293350249f   // log2(10000)/128
#define KREVL2 3.9923601817f     // log2(100 / (2*pi)) -> angles in revolutions

#define BM  128
#define BN  64
#define LDK 72                   // padded LDS k-stride (shorts)
#define MT  15                   // 1920 / 128
#define CT  38                   // 2432 / 64

typedef __attribute__((ext_vector_type(8))) short short8;
typedef __attribute__((ext_vector_type(4))) float floatx4;

// pack two f32 -> bf16 pair (round-half-up): 2 v_add + 1 v_perm
__device__ __forceinline__ unsigned pk_bf16(float lo, float hi) {
    return __builtin_amdgcn_perm(__float_as_uint(hi) + 0x8000u,
                                 __float_as_uint(lo) + 0x8000u,
                                 0x07060302u);
}

// Builder: X[hw][i] = cos(krev_i * ld) (i<128), sin (i>=128);
//          PQt[c][i] = P (i<128), Q (i>=128);  all bf16, angles in revolutions,
//          native v_sin/v_cos (|angle| <= 184 rev < 256 domain).
// 272 blocks x 256 thr: units 0..30719 -> X (hw, 8-freq seg); rest -> PQt (c, seg).
__global__ __launch_bounds__(256) void dre_build12(const float* __restrict__ pd,
                                                   const float* __restrict__ dm,
                                                   const float* __restrict__ W,
                                                   unsigned short* __restrict__ X,
                                                   unsigned short* __restrict__ PQt)
{
    const int flat = blockIdx.x * 256 + threadIdx.x;

    if (flat < HW_SZ * 16) {
        const int hw = flat >> 4, seg = flat & 15;
        const float ld = __logf(dm[hw] + 1e-5f);
        unsigned cp[4], sp[4];
#pragma unroll
        for (int jj = 0; jj < 4; ++jj) {
            const int i0 = seg * 8 + 2 * jj;
            const float k0 = exp2f(KREVL2 - (float)i0 * L2T128);
            const float k1 = exp2f(KREVL2 - (float)(i0 + 1) * L2T128);
            const float a0 = k0 * ld, a1 = k1 * ld;
            cp[jj] = pk_bf16(__builtin_amdgcn_cosf(a0), __builtin_amdgcn_cosf(a1));
            sp[jj] = pk_bf16(__builtin_amdgcn_sinf(a0), __builtin_amdgcn_sinf(a1));
        }
        *(uint4*)(X + (size_t)hw * K + seg * 8)       = make_uint4(cp[0], cp[1], cp[2], cp[3]);
        *(uint4*)(X + (size_t)hw * K + 128 + seg * 8) = make_uint4(sp[0], sp[1], sp[2], sp[3]);
    } else {
        const int v = flat - HW_SZ * 16;          // 0 .. 2432*16-1
        const int c = v >> 4, seg = v & 15;
        if (c >= NCOL) {
            const uint4 z = make_uint4(0u, 0u, 0u, 0u);
            *(uint4*)(PQt + (size_t)c * K + seg * 8)       = z;
            *(uint4*)(PQt + (size_t)c * K + 128 + seg * 8) = z;
        } else {
            const int n = c >> 3, h = c & 7;
            const float lp = __logf(fmaxf(pd[n], 0.0f) + 1e-5f);
            unsigned pp[4], qq[4];
#pragma unroll
            for (int jj = 0; jj < 4; ++jj) {
                const int i0 = seg * 8 + 2 * jj;
                const float k0 = exp2f(KREVL2 - (float)i0 * L2T128);
                const float k1 = exp2f(KREVL2 - (float)(i0 + 1) * L2T128);
                const float a0 = k0 * lp, a1 = k1 * lp;
                const float s0 = __builtin_amdgcn_sinf(a0), c0v = __builtin_amdgcn_cosf(a0);
                const float s1 = __builtin_amdgcn_sinf(a1), c1v = __builtin_amdgcn_cosf(a1);
                const float ws0 = W[i0 * 16 + h],       wc0 = W[i0 * 16 + 8 + h];
                const float ws1 = W[(i0 + 1) * 16 + h], wc1 = W[(i0 + 1) * 16 + 8 + h];
                pp[jj] = pk_bf16(ws0 * s0 + wc0 * c0v, ws1 * s1 + wc1 * c1v);
                qq[jj] = pk_bf16(wc0 * s0 - ws0 * c0v, wc1 * s1 - ws1 * c1v);
            }
            *(uint4*)(PQt + (size_t)c * K + seg * 8)       = make_uint4(pp[0], pp[1], pp[2], pp[3]);
            *(uint4*)(PQt + (size_t)c * K + 128 + seg * 8) = make_uint4(qq[0], qq[1], qq[2], qq[3]);
        }
    }
}

// Pure-MFMA GEMM (R4-verified structure): OUT[hw,c] = relu(X[hw,:].PQt[c,:] + b[h]).
// Zero transcendentals; 27.6 KB LDS -> 4-5 blk/CU; 570 blocks.
__global__ __launch_bounds__(256, 4) void dre_gemm12(const unsigned short* __restrict__ X,
                                                     const unsigned short* __restrict__ PQt,
                                                     const float* __restrict__ b,
                                                     float* __restrict__ out)
{
    __shared__ unsigned short As[BM * LDK];   // 18432 B
    __shared__ unsigned short Bs[BN * LDK];   //  9216 B

    const int tid  = threadIdx.x;
    const int w    = tid >> 6;
    const int lane = tid & 63;
    const int quad = lane >> 4;
    const int l16  = lane & 15;
    const int m0   = blockIdx.x * BM;
    const int c0   = blockIdx.y * BN;

    floatx4 acc[2][4];
#pragma unroll
    for (int mi = 0; mi < 2; ++mi)
#pragma unroll
        for (int nf = 0; nf < 4; ++nf) acc[mi][nf] = (floatx4){0.f, 0.f, 0.f, 0.f};

    for (int k0 = 0; k0 < K; k0 += 64) {
#pragma unroll
        for (int p = 0; p < 4; ++p) {
            const int row = p * 32 + (tid >> 3);
            const int cg  = (tid & 7) * 8;
            uint4 v = *(const uint4*)(X + (size_t)(m0 + row) * K + k0 + cg);
            *(uint4*)(&As[row * LDK + cg]) = v;
        }
#pragma unroll
        for (int p = 0; p < 2; ++p) {
            const int row = p * 32 + (tid >> 3);
            const int cg  = (tid & 7) * 8;
            uint4 v = *(const uint4*)(PQt + (size_t)(c0 + row) * K + k0 + cg);
            *(uint4*)(&Bs[row * LDK + cg]) = v;
        }
        __syncthreads();

#pragma unroll
        for (int ks = 0; ks < 2; ++ks) {
            const int koff = ks * 32 + quad * 8;
            short8 a0 = *(const short8*)(&As[(w * 32 + l16) * LDK + koff]);
            short8 a1 = *(const short8*)(&As[(w * 32 + 16 + l16) * LDK + koff]);
#pragma unroll
            for (int nf = 0; nf < 4; ++nf) {
                short8 bb = *(const short8*)(&Bs[(nf * 16 + l16) * LDK + koff]);
                acc[0][nf] = __builtin_amdgcn_mfma_f32_16x16x32_bf16(a0, bb, acc[0][nf], 0, 0, 0);
                acc[1][nf] = __builtin_amdgcn_mfma_f32_16x16x32_bf16(a1, bb, acc[1][nf], 0, 0, 0);
            }
        }
        __syncthreads();
    }

    // epilogue (R4-verified): C/D col=lane&15, row=quad*4+reg
    const float bias = b[lane & 7];
#pragma unroll
    for (int mi = 0; mi < 2; ++mi) {
#pragma unroll
        for (int nf = 0; nf < 4; ++nf) {
            const int c = c0 + nf * 16 + l16;
            if (c < NCOL) {
                const int n = c >> 3, h = c & 7;
                const int hw = m0 + w * 32 + mi * 16 + quad * 4;
                floatx4 v = acc[mi][nf];
                v.x = fmaxf(v.x + bias, 0.0f);
                v.y = fmaxf(v.y + bias, 0.0f);
                v.z = fmaxf(v.z + bias, 0.0f);
                v.w = fmaxf(v.w + bias, 0.0f);
                *(floatx4*)(out + (size_t)h * TOTAL + (size_t)n * HW_SZ + hw) = v;
            }
        }
    }
}

extern "C" void kernel_launch(void* const* d_in, const int* in_sizes, int n_in,
                              void* d_out, int out_size, void* d_ws, size_t ws_size,
                              hipStream_t stream) {
    const float* pd = (const float*)d_in[0];
    const float* dm = (const float*)d_in[1];
    const float* W  = (const float*)d_in[2];
    const float* b  = (const float*)d_in[3];
    float* out = (float*)d_out;

    unsigned short* X   = (unsigned short*)d_ws;                       // 983 KB
    unsigned short* PQt = (unsigned short*)((char*)d_ws + (1 << 20));  // 1.2 MB

    // units: 1920*16 (X) + 2432*16 (PQt) = 69632 = 272 * 256
    dre_build12<<<272, 256, 0, stream>>>(pd, dm, W, X, PQt);
    dre_gemm12<<<dim3(MT, CT), 256, 0, stream>>>(X, PQt, b, out);
}